// Round 8
// baseline (579.787 us; speedup 1.0000x reference)
//
#include <hip/hip_runtime.h>
#include <hip/hip_bf16.h>
#include <stdint.h>

typedef __bf16 bf16;
typedef __bf16 bf16x4 __attribute__((ext_vector_type(4)));
typedef __bf16 bf16x8 __attribute__((ext_vector_type(8)));
typedef float f32x4 __attribute__((ext_vector_type(4)));
typedef unsigned short ushort8 __attribute__((ext_vector_type(8)));

// ---- async global->LDS, 16B per lane. LDS dest wave-uniform base; HW adds lane*16.
__device__ __forceinline__ void gload16(const bf16* g, char* l) {
  __builtin_amdgcn_global_load_lds(
      reinterpret_cast<const __attribute__((address_space(1))) unsigned int*>(
          reinterpret_cast<uintptr_t>(g)),
      reinterpret_cast<__attribute__((address_space(3))) unsigned int*>(
          reinterpret_cast<uintptr_t>(l)),
      16, 0, 0);
}

#define VMCNT(n)  asm volatile("s_waitcnt vmcnt(" #n ")" ::: "memory")
#define LGKMC(n)  asm volatile("s_waitcnt lgkmcnt(" #n ")" ::: "memory")
#define SCHEDB()  __builtin_amdgcn_sched_barrier(0)

// ---- f32 -> bf16 cast, 8 elems/thread, grid-stride ----
__global__ __launch_bounds__(256) void cast_bf16(const float* __restrict__ in,
                                                 bf16* __restrict__ out, int n8) {
  int i = blockIdx.x * blockDim.x + threadIdx.x;
  const int stride = gridDim.x * blockDim.x;
  for (; i < n8; i += stride) {
    const float4 v0 = reinterpret_cast<const float4*>(in)[i * 2];
    const float4 v1 = reinterpret_cast<const float4*>(in)[i * 2 + 1];
    bf16x8 o = { (bf16)v0.x, (bf16)v0.y, (bf16)v0.z, (bf16)v0.w,
                 (bf16)v1.x, (bf16)v1.y, (bf16)v1.z, (bf16)v1.w };
    reinterpret_cast<bf16x8*>(out)[i] = o;
  }
}

// ====== pipelined NT GEMM with counted-lgkm A-frag prefetch (tile t+1 under MFMA t) ======
// C[M,N] = scale*(A[M,K].B[N,K]^T)+bias.  BM=256, BK=32, 512 thr = 8 waves.
// BN=256: waves 2M x 4N (wave-tile 128x64, MI=8); BN=128: 4M x 2N (MI=4).
// 4 LDS slots; compute slot t&3, stage t+3 -> slot (t-1)&3.
// Phase t: {bb(t) reads; stage(t+3); counted vmcnt [proves t+1]; BARRIER;
//           af(t+1) reads; SCHED; lgkmcnt(MI) [drains af(t)+bb(t), leaves af(t+1)
//           in flight]; SCHED; 4*MI MFMA(t); counted... ; BARRIER}.
// The af(t+1) LDS drain overlaps MFMA(t) -- the counted-lgkm analog of T4.
// Race ledger (unchanged from R6): reads of slot t-1 drained pre-ENDBAR(t-1);
// stage(t+3) issues post-ENDBAR(t-1).  DS FIFO per wave is in-order (no SMEM/
// ds_write in loop) -> lgkmcnt(MI) leaves exactly the MI newest reads.
template <bool OUT_BF16, bool HAS_BIAS, int BN>
__global__ __launch_bounds__(512, 2) void gemm_pipe(
    const bf16* __restrict__ A, const bf16* __restrict__ B,
    const float* __restrict__ bias, void* __restrict__ Cout,
    int M, int N, int K, float scale) {
  constexpr int BM = 256;
  constexpr int SLOT = (BM + BN) * 64;           // bytes per slot
  constexpr int BOFF = BM * 64;                  // B region offset in slot
  constexpr int TM = (BN == 256) ? 128 : 64;     // wave-tile M
  constexpr int MI = TM / 16;                    // 8 or 4
  constexpr int NI = 4;                          // wave-tile N = 64
  extern __shared__ char lds[];
  const int tid = threadIdx.x;
  const int lane = tid & 63, w = tid >> 6;

  // block mapping: bijective XCD chunking (m204), n-fast within chunk (L2 A-reuse)
  const int gridN = N / BN;
  const int nwg = gridDim.x;
  const int orig = blockIdx.x;
  int wgid;
  { const int q = nwg >> 3, r = nwg & 7, x = orig & 7, rest = orig >> 3;
    wgid = (x < r ? x * (q + 1) : r * (q + 1) + (x - r) * q) + rest; }
  const int m0 = (wgid / gridN) * BM;
  const int n0 = (wgid % gridN) * BN;

  // ---- staging source (pre-swizzled global col so linear LDS dest = swizzled) ----
  const int srow = w * 16 + (lane >> 2);               // 0..127
  const int scol = (((lane & 3) ^ ((srow >> 1) & 3))) * 8;
  const bf16* gA  = A + (size_t)(m0 + srow) * K + scol;
  const bf16* gA2 = gA + (size_t)128 * K;
  const bf16* gB  = B + (size_t)(n0 + srow) * K + scol;
  const bf16* gB2 = (BN == 256) ? gB + (size_t)128 * K : gB;

  auto stage = [&](int T) {
    char* sb = lds + (size_t)(T & 3) * SLOT;
    const int kc = T * 32;
    gload16(gA + kc,  sb + w * 1024);
    gload16(gA2 + kc, sb + 8192 + w * 1024);
    gload16(gB + kc,  sb + BOFF + w * 1024);
    if constexpr (BN == 256) gload16(gB2 + kc, sb + BOFF + 8192 + w * 1024);
  };

  // ---- fragment read offsets (swizzled); (row>>1)&3 invariant under +16 rows ----
  const int fr = lane & 15, hi = lane >> 4;
  int wm, wn;
  if constexpr (BN == 256) { wm = w >> 2; wn = w & 3; }
  else                     { wm = w >> 1; wn = w & 1; }
  const int arow = wm * TM + fr;
  const int aoff0 = arow * 64 + ((hi ^ ((arow >> 1) & 3)) << 4);
  const int brow = wn * 64 + fr;
  const int boff0 = BOFF + brow * 64 + ((hi ^ ((brow >> 1) & 3)) << 4);

  f32x4 acc[MI][NI] = {};
  const int NT = K >> 5;   // even for all our shapes (32/64/128)

  bf16x8 afA[MI], afB[MI];

  // prologue: stage tiles 0,1,2; prove tile 0; collective; read af(0) into set A
  stage(0); stage(1); stage(2);
  if constexpr (BN == 256) VMCNT(8); else VMCNT(6);
  __builtin_amdgcn_s_barrier();
  SCHEDB();
#pragma unroll
  for (int i = 0; i < MI; ++i) afA[i] = *(const bf16x8*)(lds + aoff0 + i * 1024);

#define PHASE(T, AFC, AFN) do {                                                \
    const char* sb_ = lds + (size_t)((T) & 3) * SLOT;                          \
    bf16x8 bb_[NI];                                                            \
    _Pragma("unroll") for (int i = 0; i < NI; ++i)                             \
      bb_[i] = *(const bf16x8*)(sb_ + boff0 + i * 1024);                       \
    if ((T) + 3 < NT) {                                                        \
      stage((T) + 3);                                                          \
      if constexpr (BN == 256) VMCNT(8); else VMCNT(6);                        \
    } else if ((T) + 2 < NT) {                                                 \
      if constexpr (BN == 256) VMCNT(4); else VMCNT(3);                        \
    } else if ((T) + 1 < NT) {                                                 \
      VMCNT(0);                                                                \
    }                                                                          \
    __builtin_amdgcn_s_barrier();                                              \
    SCHEDB();                                                                  \
    if ((T) + 1 < NT) {                                                        \
      const char* nb_ = lds + (size_t)(((T) + 1) & 3) * SLOT;                  \
      _Pragma("unroll") for (int i = 0; i < MI; ++i)                           \
        AFN[i] = *(const bf16x8*)(nb_ + aoff0 + i * 1024);                     \
      SCHEDB();                                                                \
      if constexpr (BN == 256) LGKMC(8); else LGKMC(4);                        \
    } else {                                                                   \
      LGKMC(0);                                                                \
    }                                                                          \
    SCHEDB();                                                                  \
    __builtin_amdgcn_s_setprio(1);                                             \
    _Pragma("unroll") for (int mi = 0; mi < MI; ++mi)                          \
      _Pragma("unroll") for (int ni = 0; ni < NI; ++ni)                        \
        acc[mi][ni] = __builtin_amdgcn_mfma_f32_16x16x32_bf16(                 \
            AFC[mi], bb_[ni], acc[mi][ni], 0, 0, 0);                           \
    __builtin_amdgcn_s_setprio(0);                                             \
    __builtin_amdgcn_s_barrier();                                              \
  } while (0)

  for (int t = 0; t < NT; t += 2) {
    PHASE(t, afA, afB);
    PHASE(t + 1, afB, afA);
  }
#undef PHASE

  // epilogue: C/D layout col = lane&15, row = (lane>>4)*4 + j  [m89-verified]
  const int lro = hi * 4;
#pragma unroll
  for (int ni = 0; ni < NI; ++ni) {
    const int gcol = n0 + wn * 64 + ni * 16 + fr;
    float bvs = 0.f;
    if constexpr (HAS_BIAS) bvs = bias[gcol];
#pragma unroll
    for (int mi = 0; mi < MI; ++mi) {
      const int grow = m0 + wm * TM + mi * 16 + lro;
#pragma unroll
      for (int j = 0; j < 4; ++j) {
        const float c = acc[mi][ni][j] * scale + bvs;
        if constexpr (OUT_BF16)
          ((bf16*)Cout)[(size_t)(grow + j) * N + gcol] = (bf16)c;
        else
          ((float*)Cout)[(size_t)(grow + j) * N + gcol] = c;
      }
    }
  }
}

// ---------------- prep: W3t[e,k] = bf16(prior[k] * dic_z[k,e]), transposed ----------------
__global__ __launch_bounds__(256) void prep_w3t(const float* __restrict__ dic,
                                                const float* __restrict__ prior,
                                                bf16* __restrict__ w3t) {
  const int KD = 4096, E = 2048;
  __shared__ bf16 t[64][72];
  const int k0 = blockIdx.x * 64, e0 = blockIdx.y * 64;
  const int tid = threadIdx.x;
  const int er = (tid & 15) * 4;
  const int kr = tid >> 4;
#pragma unroll
  for (int p = 0; p < 4; ++p) {
    const int k = kr + p * 16;
    const float pr = prior[k0 + k];
    const float4 v = *reinterpret_cast<const float4*>(dic + (size_t)(k0 + k) * E + e0 + er);
    t[er + 0][k] = (bf16)(v.x * pr);
    t[er + 1][k] = (bf16)(v.y * pr);
    t[er + 2][k] = (bf16)(v.z * pr);
    t[er + 3][k] = (bf16)(v.w * pr);
  }
  __syncthreads();
  const int e = tid >> 2, kc = (tid & 3) * 16;
  ushort8 a = *reinterpret_cast<ushort8*>(&t[e][kc]);
  ushort8 b = *reinterpret_cast<ushort8*>(&t[e][kc + 8]);
  unsigned short* dst = (unsigned short*)w3t + (size_t)(e0 + e) * KD + k0 + kc;
  *reinterpret_cast<ushort8*>(dst) = a;
  *reinterpret_cast<ushort8*>(dst + 8) = b;
}

// ---------------- in-place row softmax over bf16 logits [M rows x 4096] ----------------
__global__ __launch_bounds__(256) void softmax_rows(unsigned short* __restrict__ S) {
  const int K = 4096;
  unsigned short* row = S + (size_t)blockIdx.x * K;
  const int tid = threadIdx.x;
  const int lane = tid & 63, w = tid >> 6;
  __shared__ float red[8];

  ushort8 v0 = *reinterpret_cast<const ushort8*>(row + tid * 8);
  ushort8 v1 = *reinterpret_cast<const ushort8*>(row + 2048 + tid * 8);
  float x[16];
#pragma unroll
  for (int i = 0; i < 8; ++i) {
    x[i]     = __uint_as_float(((unsigned)v0[i]) << 16);
    x[8 + i] = __uint_as_float(((unsigned)v1[i]) << 16);
  }
  float mx = x[0];
#pragma unroll
  for (int i = 1; i < 16; ++i) mx = fmaxf(mx, x[i]);
#pragma unroll
  for (int o = 32; o; o >>= 1) mx = fmaxf(mx, __shfl_xor(mx, o));
  if (lane == 0) red[w] = mx;
  __syncthreads();
  mx = fmaxf(fmaxf(red[0], red[1]), fmaxf(red[2], red[3]));

  float s = 0.f;
#pragma unroll
  for (int i = 0; i < 16; ++i) { x[i] = __expf(x[i] - mx); s += x[i]; }
#pragma unroll
  for (int o = 32; o; o >>= 1) s += __shfl_xor(s, o);
  if (lane == 0) red[4 + w] = s;
  __syncthreads();
  const float inv = 1.f / (red[4] + red[5] + red[6] + red[7]);

  ushort8 o0, o1;
#pragma unroll
  for (int i = 0; i < 8; ++i) {
    bf16 b0 = (bf16)(x[i] * inv);
    bf16 b1 = (bf16)(x[8 + i] * inv);
    o0[i] = __builtin_bit_cast(unsigned short, b0);
    o1[i] = __builtin_bit_cast(unsigned short, b1);
  }
  *reinterpret_cast<ushort8*>(row + tid * 8) = o0;
  *reinterpret_cast<ushort8*>(row + 2048 + tid * 8) = o1;
}

extern "C" void kernel_launch(void* const* d_in, const int* in_sizes, int n_in,
                              void* d_out, int out_size, void* d_ws, size_t ws_size,
                              hipStream_t stream) {
  const float* y     = (const float*)d_in[0];  // [16384,1024]
  const float* Wy_w  = (const float*)d_in[1];  // [1024,1024]
  const float* Wy_b  = (const float*)d_in[2];  // [1024]
  const float* Wz_w  = (const float*)d_in[3];  // [1024,2048]
  const float* Wz_b  = (const float*)d_in[4];  // [1024]
  const float* dic   = (const float*)d_in[5];  // [4096,2048]
  const float* prior = (const float*)d_in[6];  // [4096]
  float* z = (float*)d_out;                    // [16384,2048]

  const int M = 16384, D = 1024, E = 2048, KD = 4096;

  char* ws = (char*)d_ws;
  bf16* w3t  = (bf16*)(ws);
  bf16* h    = (bf16*)(ws + ((size_t)16 << 20));
  bf16* dzb  = (bf16*)(ws + ((size_t)48 << 20));
  bf16* S    = (bf16*)(ws + ((size_t)56 << 20));
  bf16* yb   = (bf16*)(ws + ((size_t)56 << 20));
  bf16* Wyb  = (bf16*)(ws + ((size_t)88 << 20));
  bf16* Wzb  = (bf16*)(ws + ((size_t)90 << 20));
  bf16* dicb = (bf16*)(ws + ((size_t)94 << 20));

  // 0) pre-cast f32 operands to bf16
  cast_bf16<<<2048, 256, 0, stream>>>(y, yb, M * D / 8);
  cast_bf16<<<512, 256, 0, stream>>>(Wy_w, Wyb, D * D / 8);
  cast_bf16<<<512, 256, 0, stream>>>(Wz_w, Wzb, D * E / 8);
  cast_bf16<<<1024, 256, 0, stream>>>(dic, dicb, KD * E / 8);
  // 1) W3t[e,k] = prior[k] * dic_z[k,e]
  prep_w3t<<<dim3(KD / 64, E / 64), 256, 0, stream>>>(dic, prior, w3t);
  // 2) h = yb . Wyb^T + Wy_b   -> bf16 [16384,1024]   grid 256
  gemm_pipe<true, true, 256><<<(M / 256) * (D / 256), 512, 131072, stream>>>(
      yb, Wyb, Wy_b, h, M, D, D, 1.0f);
  // 3) dz = dicb . Wzb^T + Wz_b -> bf16 [4096,1024]   grid 128
  gemm_pipe<true, true, 128><<<(KD / 256) * (D / 128), 512, 98304, stream>>>(
      dicb, Wzb, Wz_b, dzb, KD, D, E, 1.0f);
  // 4) S = (h . dz^T) / 32      -> bf16 [16384,4096]  grid 1024
  gemm_pipe<true, false, 256><<<(M / 256) * (KD / 256), 512, 131072, stream>>>(
      h, dzb, nullptr, S, M, KD, D, 0.03125f);
  // 5) row softmax in place
  softmax_rows<<<M, 256, 0, stream>>>((unsigned short*)S);
  // 6) z = att . w3t^T          -> f32 [16384,2048]   grid 512
  gemm_pipe<false, false, 256><<<(M / 256) * (E / 256), 512, 131072, stream>>>(
      S, w3t, nullptr, z, M, E, KD, 1.0f);
}

// Round 9
// 562.214 us; speedup vs baseline: 1.0313x; 1.0313x over previous
//
#include <hip/hip_runtime.h>
#include <hip/hip_bf16.h>
#include <stdint.h>

typedef __bf16 bf16;
typedef __bf16 bf16x8 __attribute__((ext_vector_type(8)));
typedef float f32x4 __attribute__((ext_vector_type(4)));
typedef unsigned short ushort8 __attribute__((ext_vector_type(8)));

// ---- async global->LDS, 16B per lane. LDS dest wave-uniform base; HW adds lane*16.
__device__ __forceinline__ void gload16(const bf16* g, char* l) {
  __builtin_amdgcn_global_load_lds(
      reinterpret_cast<const __attribute__((address_space(1))) unsigned int*>(
          reinterpret_cast<uintptr_t>(g)),
      reinterpret_cast<__attribute__((address_space(3))) unsigned int*>(
          reinterpret_cast<uintptr_t>(l)),
      16, 0, 0);
}

#define VMCNT(n)  asm volatile("s_waitcnt vmcnt(" #n ")" ::: "memory")
#define LGKM0()   do { asm volatile("s_waitcnt lgkmcnt(0)" ::: "memory"); \
                       __builtin_amdgcn_sched_barrier(0); } while (0)
#define BAR()     __builtin_amdgcn_s_barrier()

// ---- f32 -> bf16 cast, 8 elems/thread, grid-stride ----
__global__ __launch_bounds__(256) void cast_bf16(const float* __restrict__ in,
                                                 bf16* __restrict__ out, int n8) {
  int i = blockIdx.x * blockDim.x + threadIdx.x;
  const int stride = gridDim.x * blockDim.x;
  for (; i < n8; i += stride) {
    const float4 v0 = reinterpret_cast<const float4*>(in)[i * 2];
    const float4 v1 = reinterpret_cast<const float4*>(in)[i * 2 + 1];
    bf16x8 o = { (bf16)v0.x, (bf16)v0.y, (bf16)v0.z, (bf16)v0.w,
                 (bf16)v1.x, (bf16)v1.y, (bf16)v1.z, (bf16)v1.w };
    reinterpret_cast<bf16x8*>(out)[i] = o;
  }
}

// ================= m201-geometry 8-phase NT GEMM =================
// C[M,N] = scale*(A[M,K].B[N,K]^T)+bias.  BM=256, BK=64, 512 thr = 8 waves.
// BN=256: waves 2M x 4N (wave-tile 128x64, MI=8, 4 phases/K-step).
// BN=128: waves 4M x 2N (wave-tile 64x64, MI=4, 2 phases/K-step).
// LDS: 2 double-buffers of {A[256][64] 32KB + B[BN][64]}.  Per K-step u:
//  q1: read B all 8 frags + A(mi0-1) [12 ds_read]; stage A-lo(u+1); BAR;
//      lgkm0; 16 MFMA; BAR
//  q2: read A(mi2-3); stage A-hi(u+1); BAR; lgkm0; 16 MFMA; BAR
//  q3: read A(mi4-5); stage B-lo(u+2); ...
//  q4: read A(mi6-7); stage B-hi(u+2); BAR; lgkm0; 16 MFMA; vmcnt(4); BAR
// Region reuse ledger: B(u) region free after q1 END-bar (all B reads drained
// by q1 lgkm0) -> q3/q4 stage B(u+2) there.  A(u-1) free after q4(u-1) END-bar
// -> q1/q2(u) stage A(u+1) into buf (u+1)&1.  FIFO at q4(u): [B(u+1) 4,
// A(u+1) 4, B(u+2) 4] -> vmcnt(4) proves step u+1 landed; END-bar collective.
// Swizzle: 16B-chunk c (0..7 per 128B row) XOR (row&7), both sides.
template <bool OUT_BF16, bool HAS_BIAS, int BN>
__global__ __launch_bounds__(512, 2) void gemm8(
    const bf16* __restrict__ A, const bf16* __restrict__ B,
    const float* __restrict__ bias, void* __restrict__ Cout,
    int M, int N, int K, float scale) {
  constexpr int BUFSZ = 32768 + BN * 128;        // A 32KB + B
  constexpr int BOFF = 32768;
  constexpr int TM = (BN == 256) ? 128 : 64;
  constexpr int MI = TM / 16;
  constexpr int NI = 4;
  constexpr int NPH = MI / 2;                    // phases per K-step
  extern __shared__ char lds[];
  const int tid = threadIdx.x;
  const int lane = tid & 63, w = tid >> 6;

  // bijective XCD chunking (m204), n-fast within chunk (L2 A-reuse)
  const int gridN = N / BN;
  const int nwg = gridDim.x;
  const int orig = blockIdx.x;
  int wgid;
  { const int q = nwg >> 3, r = nwg & 7, x = orig & 7, rest = orig >> 3;
    wgid = (x < r ? x * (q + 1) : r * (q + 1) + (x - r) * q) + rest; }
  const int m0 = (wgid / gridN) * 256;
  const int n0 = (wgid % gridN) * BN;

  // staging source: pre-swizzled chunk so linear LDS dest = swizzled layout
  const int srow = lane >> 3;                         // 0..7
  const int scol = ((lane & 7) ^ srow) * 8;           // chunk^row&7, elems
  const bf16* gA = A + (size_t)(m0 + w * 8 + srow) * K + scol;
  const bf16* gB = B + (size_t)(n0 + w * 8 + srow) * K + scol;

  // one half = 16KB = 2 cooperative gloads (rows base..base+63, base+64..)
  auto stA = [&](char* dst, int u, int h) {
    gload16(gA + (size_t)(h * 128) * K + (size_t)u * 64, dst + h * 16384 + w * 1024);
    gload16(gA + (size_t)(h * 128 + 64) * K + (size_t)u * 64, dst + h * 16384 + 8192 + w * 1024);
  };
  auto stB = [&](char* dst, int u, int h) {
    gload16(gB + (size_t)(h * 128) * K + (size_t)u * 64, dst + BOFF + h * 16384 + w * 1024);
    gload16(gB + (size_t)(h * 128 + 64) * K + (size_t)u * 64, dst + BOFF + h * 16384 + 8192 + w * 1024);
  };

  // fragment read bases (swizzled): row*128 + ((ks*4+hi)^(fr&7))*16
  const int fr = lane & 15, hi = lane >> 4;
  int wm, wn;
  if constexpr (BN == 256) { wm = w >> 2; wn = w & 3; }
  else                     { wm = w >> 1; wn = w & 1; }
  const int abase = (wm * TM + fr) * 128 + ((hi ^ (fr & 7)) << 4);
  const int bbase = BOFF + (wn * 64 + fr) * 128 + ((hi ^ (fr & 7)) << 4);
#define RD_A(b, mi, ks) (*(const bf16x8*)((b) + ((abase + (mi) * 2048) ^ ((ks) << 6))))
#define RD_B(b, ni, ks) (*(const bf16x8*)((b) + ((bbase + (ni) * 2048) ^ ((ks) << 6))))

  f32x4 acc[MI][NI] = {};
  const int NT = K >> 6;

  // prologue: A(0), B(0), B(1); prove A(0)+B(0)
  stA(lds, 0, 0); stA(lds, 0, 1);
  stB(lds, 0, 0);
  if constexpr (BN == 256) stB(lds, 0, 1);
  stB(lds + BUFSZ, 1, 0);
  if constexpr (BN == 256) { stB(lds + BUFSZ, 1, 1); VMCNT(4); }
  else                     { VMCNT(2); }
  BAR();

  for (int u = 0; u < NT; ++u) {
    char* b  = lds + (size_t)(u & 1) * BUFSZ;
    char* bn = lds + (size_t)((u + 1) & 1) * BUFSZ;
    bf16x8 bb[2][NI], a[2][2];
    const bool sA = (u + 1) < NT, sB = (u + 2) < NT;

    if constexpr (BN == 256) {
      // ---- q1: B all + A(0,1); stage A-lo(u+1) ----
      a[0][0] = RD_A(b, 0, 0); a[0][1] = RD_A(b, 0, 1);
      a[1][0] = RD_A(b, 1, 0); a[1][1] = RD_A(b, 1, 1);
#pragma unroll
      for (int ni = 0; ni < NI; ++ni) { bb[0][ni] = RD_B(b, ni, 0); bb[1][ni] = RD_B(b, ni, 1); }
      if (sA) stA(bn, u + 1, 0);
      BAR(); LGKM0();
      __builtin_amdgcn_s_setprio(1);
#pragma unroll
      for (int m2 = 0; m2 < 2; ++m2)
#pragma unroll
        for (int ni = 0; ni < NI; ++ni) {
          acc[m2][ni] = __builtin_amdgcn_mfma_f32_16x16x32_bf16(a[m2][0], bb[0][ni], acc[m2][ni], 0, 0, 0);
          acc[m2][ni] = __builtin_amdgcn_mfma_f32_16x16x32_bf16(a[m2][1], bb[1][ni], acc[m2][ni], 0, 0, 0);
        }
      __builtin_amdgcn_s_setprio(0);
      BAR();
      // ---- q2: A(2,3); stage A-hi(u+1) ----
      a[0][0] = RD_A(b, 2, 0); a[0][1] = RD_A(b, 2, 1);
      a[1][0] = RD_A(b, 3, 0); a[1][1] = RD_A(b, 3, 1);
      if (sA) stA(bn, u + 1, 1);
      BAR(); LGKM0();
      __builtin_amdgcn_s_setprio(1);
#pragma unroll
      for (int m2 = 0; m2 < 2; ++m2)
#pragma unroll
        for (int ni = 0; ni < NI; ++ni) {
          acc[2 + m2][ni] = __builtin_amdgcn_mfma_f32_16x16x32_bf16(a[m2][0], bb[0][ni], acc[2 + m2][ni], 0, 0, 0);
          acc[2 + m2][ni] = __builtin_amdgcn_mfma_f32_16x16x32_bf16(a[m2][1], bb[1][ni], acc[2 + m2][ni], 0, 0, 0);
        }
      __builtin_amdgcn_s_setprio(0);
      BAR();
      // ---- q3: A(4,5); stage B-lo(u+2) ----
      a[0][0] = RD_A(b, 4, 0); a[0][1] = RD_A(b, 4, 1);
      a[1][0] = RD_A(b, 5, 0); a[1][1] = RD_A(b, 5, 1);
      if (sB) stB(b, u + 2, 0);
      BAR(); LGKM0();
      __builtin_amdgcn_s_setprio(1);
#pragma unroll
      for (int m2 = 0; m2 < 2; ++m2)
#pragma unroll
        for (int ni = 0; ni < NI; ++ni) {
          acc[4 + m2][ni] = __builtin_amdgcn_mfma_f32_16x16x32_bf16(a[m2][0], bb[0][ni], acc[4 + m2][ni], 0, 0, 0);
          acc[4 + m2][ni] = __builtin_amdgcn_mfma_f32_16x16x32_bf16(a[m2][1], bb[1][ni], acc[4 + m2][ni], 0, 0, 0);
        }
      __builtin_amdgcn_s_setprio(0);
      BAR();
      // ---- q4: A(6,7); stage B-hi(u+2); counted vmcnt ----
      a[0][0] = RD_A(b, 6, 0); a[0][1] = RD_A(b, 6, 1);
      a[1][0] = RD_A(b, 7, 0); a[1][1] = RD_A(b, 7, 1);
      if (sB) stB(b, u + 2, 1);
      BAR(); LGKM0();
      __builtin_amdgcn_s_setprio(1);
#pragma unroll
      for (int m2 = 0; m2 < 2; ++m2)
#pragma unroll
        for (int ni = 0; ni < NI; ++ni) {
          acc[6 + m2][ni] = __builtin_amdgcn_mfma_f32_16x16x32_bf16(a[m2][0], bb[0][ni], acc[6 + m2][ni], 0, 0, 0);
          acc[6 + m2][ni] = __builtin_amdgcn_mfma_f32_16x16x32_bf16(a[m2][1], bb[1][ni], acc[6 + m2][ni], 0, 0, 0);
        }
      __builtin_amdgcn_s_setprio(0);
      if (sB) VMCNT(4); else VMCNT(0);
      BAR();
    } else {
      // ---- q1: B all + A(0,1); stage A-lo+A-hi(u+1) ----
      a[0][0] = RD_A(b, 0, 0); a[0][1] = RD_A(b, 0, 1);
      a[1][0] = RD_A(b, 1, 0); a[1][1] = RD_A(b, 1, 1);
#pragma unroll
      for (int ni = 0; ni < NI; ++ni) { bb[0][ni] = RD_B(b, ni, 0); bb[1][ni] = RD_B(b, ni, 1); }
      if (sA) { stA(bn, u + 1, 0); stA(bn, u + 1, 1); }
      BAR(); LGKM0();
      __builtin_amdgcn_s_setprio(1);
#pragma unroll
      for (int m2 = 0; m2 < 2; ++m2)
#pragma unroll
        for (int ni = 0; ni < NI; ++ni) {
          acc[m2][ni] = __builtin_amdgcn_mfma_f32_16x16x32_bf16(a[m2][0], bb[0][ni], acc[m2][ni], 0, 0, 0);
          acc[m2][ni] = __builtin_amdgcn_mfma_f32_16x16x32_bf16(a[m2][1], bb[1][ni], acc[m2][ni], 0, 0, 0);
        }
      __builtin_amdgcn_s_setprio(0);
      BAR();
      // ---- q2: A(2,3); stage B(u+2); counted vmcnt ----
      a[0][0] = RD_A(b, 2, 0); a[0][1] = RD_A(b, 2, 1);
      a[1][0] = RD_A(b, 3, 0); a[1][1] = RD_A(b, 3, 1);
      if (sB) stB(b, u + 2, 0);
      BAR(); LGKM0();
      __builtin_amdgcn_s_setprio(1);
#pragma unroll
      for (int m2 = 0; m2 < 2; ++m2)
#pragma unroll
        for (int ni = 0; ni < NI; ++ni) {
          acc[2 + m2][ni] = __builtin_amdgcn_mfma_f32_16x16x32_bf16(a[m2][0], bb[0][ni], acc[2 + m2][ni], 0, 0, 0);
          acc[2 + m2][ni] = __builtin_amdgcn_mfma_f32_16x16x32_bf16(a[m2][1], bb[1][ni], acc[2 + m2][ni], 0, 0, 0);
        }
      __builtin_amdgcn_s_setprio(0);
      if (sB) VMCNT(2); else VMCNT(0);
      BAR();
    }
  }
#undef RD_A
#undef RD_B

  // epilogue: C/D layout col = lane&15, row = (lane>>4)*4 + j  [m89-verified]
  const int lro = hi * 4;
#pragma unroll
  for (int ni = 0; ni < NI; ++ni) {
    const int gcol = n0 + wn * 64 + ni * 16 + fr;
    float bvs = 0.f;
    if constexpr (HAS_BIAS) bvs = bias[gcol];
#pragma unroll
    for (int mi = 0; mi < MI; ++mi) {
      const int grow = m0 + wm * TM + mi * 16 + lro;
#pragma unroll
      for (int j = 0; j < 4; ++j) {
        const float c = acc[mi][ni][j] * scale + bvs;
        if constexpr (OUT_BF16)
          ((bf16*)Cout)[(size_t)(grow + j) * N + gcol] = (bf16)c;
        else
          ((float*)Cout)[(size_t)(grow + j) * N + gcol] = c;
      }
    }
  }
}

// ---------------- prep: W3t[e,k] = bf16(prior[k] * dic_z[k,e]), transposed ----------------
__global__ __launch_bounds__(256) void prep_w3t(const float* __restrict__ dic,
                                                const float* __restrict__ prior,
                                                bf16* __restrict__ w3t) {
  const int KD = 4096, E = 2048;
  __shared__ bf16 t[64][72];
  const int k0 = blockIdx.x * 64, e0 = blockIdx.y * 64;
  const int tid = threadIdx.x;
  const int er = (tid & 15) * 4;
  const int kr = tid >> 4;
#pragma unroll
  for (int p = 0; p < 4; ++p) {
    const int k = kr + p * 16;
    const float pr = prior[k0 + k];
    const float4 v = *reinterpret_cast<const float4*>(dic + (size_t)(k0 + k) * E + e0 + er);
    t[er + 0][k] = (bf16)(v.x * pr);
    t[er + 1][k] = (bf16)(v.y * pr);
    t[er + 2][k] = (bf16)(v.z * pr);
    t[er + 3][k] = (bf16)(v.w * pr);
  }
  __syncthreads();
  const int e = tid >> 2, kc = (tid & 3) * 16;
  ushort8 a = *reinterpret_cast<ushort8*>(&t[e][kc]);
  ushort8 b = *reinterpret_cast<ushort8*>(&t[e][kc + 8]);
  unsigned short* dst = (unsigned short*)w3t + (size_t)(e0 + e) * KD + k0 + kc;
  *reinterpret_cast<ushort8*>(dst) = a;
  *reinterpret_cast<ushort8*>(dst + 8) = b;
}

// ---------------- in-place row softmax over bf16 logits [M rows x 4096] ----------------
__global__ __launch_bounds__(256) void softmax_rows(unsigned short* __restrict__ S) {
  const int K = 4096;
  unsigned short* row = S + (size_t)blockIdx.x * K;
  const int tid = threadIdx.x;
  const int lane = tid & 63, w = tid >> 6;
  __shared__ float red[8];

  ushort8 v0 = *reinterpret_cast<const ushort8*>(row + tid * 8);
  ushort8 v1 = *reinterpret_cast<const ushort8*>(row + 2048 + tid * 8);
  float x[16];
#pragma unroll
  for (int i = 0; i < 8; ++i) {
    x[i]     = __uint_as_float(((unsigned)v0[i]) << 16);
    x[8 + i] = __uint_as_float(((unsigned)v1[i]) << 16);
  }
  float mx = x[0];
#pragma unroll
  for (int i = 1; i < 16; ++i) mx = fmaxf(mx, x[i]);
#pragma unroll
  for (int o = 32; o; o >>= 1) mx = fmaxf(mx, __shfl_xor(mx, o));
  if (lane == 0) red[w] = mx;
  __syncthreads();
  mx = fmaxf(fmaxf(red[0], red[1]), fmaxf(red[2], red[3]));

  float s = 0.f;
#pragma unroll
  for (int i = 0; i < 16; ++i) { x[i] = __expf(x[i] - mx); s += x[i]; }
#pragma unroll
  for (int o = 32; o; o >>= 1) s += __shfl_xor(s, o);
  if (lane == 0) red[4 + w] = s;
  __syncthreads();
  const float inv = 1.f / (red[4] + red[5] + red[6] + red[7]);

  ushort8 o0, o1;
#pragma unroll
  for (int i = 0; i < 8; ++i) {
    bf16 b0 = (bf16)(x[i] * inv);
    bf16 b1 = (bf16)(x[8 + i] * inv);
    o0[i] = __builtin_bit_cast(unsigned short, b0);
    o1[i] = __builtin_bit_cast(unsigned short, b1);
  }
  *reinterpret_cast<ushort8*>(row + tid * 8) = o0;
  *reinterpret_cast<ushort8*>(row + 2048 + tid * 8) = o1;
}

extern "C" void kernel_launch(void* const* d_in, const int* in_sizes, int n_in,
                              void* d_out, int out_size, void* d_ws, size_t ws_size,
                              hipStream_t stream) {
  const float* y     = (const float*)d_in[0];  // [16384,1024]
  const float* Wy_w  = (const float*)d_in[1];  // [1024,1024]
  const float* Wy_b  = (const float*)d_in[2];  // [1024]
  const float* Wz_w  = (const float*)d_in[3];  // [1024,2048]
  const float* Wz_b  = (const float*)d_in[4];  // [1024]
  const float* dic   = (const float*)d_in[5];  // [4096,2048]
  const float* prior = (const float*)d_in[6];  // [4096]
  float* z = (float*)d_out;                    // [16384,2048]

  const int M = 16384, D = 1024, E = 2048, KD = 4096;

  char* ws = (char*)d_ws;
  bf16* w3t  = (bf16*)(ws);
  bf16* h    = (bf16*)(ws + ((size_t)16 << 20));
  bf16* dzb  = (bf16*)(ws + ((size_t)48 << 20));
  bf16* S    = (bf16*)(ws + ((size_t)56 << 20));
  bf16* yb   = (bf16*)(ws + ((size_t)56 << 20));
  bf16* Wyb  = (bf16*)(ws + ((size_t)88 << 20));
  bf16* Wzb  = (bf16*)(ws + ((size_t)90 << 20));
  bf16* dicb = (bf16*)(ws + ((size_t)94 << 20));

  // 0) pre-cast f32 operands to bf16
  cast_bf16<<<2048, 256, 0, stream>>>(y, yb, M * D / 8);
  cast_bf16<<<512, 256, 0, stream>>>(Wy_w, Wyb, D * D / 8);
  cast_bf16<<<512, 256, 0, stream>>>(Wz_w, Wzb, D * E / 8);
  cast_bf16<<<1024, 256, 0, stream>>>(dic, dicb, KD * E / 8);
  // 1) W3t[e,k] = prior[k] * dic_z[k,e]
  prep_w3t<<<dim3(KD / 64, E / 64), 256, 0, stream>>>(dic, prior, w3t);
  // 2) h = yb . Wyb^T + Wy_b   -> bf16 [16384,1024]   grid 256
  gemm8<true, true, 256><<<(M / 256) * (D / 256), 512, 131072, stream>>>(
      yb, Wyb, Wy_b, h, M, D, D, 1.0f);
  // 3) dz = dicb . Wzb^T + Wz_b -> bf16 [4096,1024]   grid 128
  gemm8<true, true, 128><<<(KD / 256) * (D / 128), 512, 98304, stream>>>(
      dicb, Wzb, Wz_b, dzb, KD, D, E, 1.0f);
  // 4) S = (h . dz^T) / 32      -> bf16 [16384,4096]  grid 1024
  gemm8<true, false, 256><<<(M / 256) * (KD / 256), 512, 131072, stream>>>(
      h, dzb, nullptr, S, M, KD, D, 0.03125f);
  // 5) row softmax in place
  softmax_rows<<<M, 256, 0, stream>>>((unsigned short*)S);
  // 6) z = att . w3t^T          -> f32 [16384,2048]   grid 512
  gemm8<false, false, 256><<<(M / 256) * (E / 256), 512, 131072, stream>>>(
      S, w3t, nullptr, z, M, E, KD, 1.0f);
}